// Round 6
// baseline (345.901 us; speedup 1.0000x reference)
//
#include <hip/hip_runtime.h>
#include <math.h>

// SioConvLayer fused forward, MI355X (r6).
// r5: 311.3us. k_attn was top real kernel (57us, Occ 10%, 1 block/CU @ 101KB LDS).
// r6: (1) k_attn -> 2 LDS buffers (51KB), 512 blocks (32 rows each), phase
//     reorder (cross-state first, eD applied post-hoc; qck overwrites dead qp).
//     (2) serial k_state_scan -> parallel k_states (272 blocks): scalar decay
//     P_c telescopes => S_states[c] = exp(D_c) S_init + sum_{c'<c} exp(D_c-E_c') T_c'.
// GEMMs and all other kernels byte-identical to r5 (validated, conflict-free).

#define LSEQ 1024
#define NCHUNK 16
#define CHK 64

typedef float2 cf;
typedef unsigned short u16;
typedef unsigned int u32;
typedef __bf16 b16x8 __attribute__((ext_vector_type(8)));
typedef float f32x4 __attribute__((ext_vector_type(4)));

__device__ __forceinline__ cf cmul(cf a, cf b){
  return make_float2(a.x*b.x - a.y*b.y, a.x*b.y + a.y*b.x);
}
__device__ __forceinline__ cf cfma(cf a, cf b, cf c){
  c.x = fmaf(a.x, b.x, fmaf(-a.y, b.y, c.x));
  c.y = fmaf(a.x, b.y, fmaf( a.y, b.x, c.y));
  return c;
}
__device__ __forceinline__ cf cexpf2(cf a){
  float e = expf(a.x); float s, c; sincosf(a.y, &s, &c);
  return make_float2(e*c, e*s);
}
__device__ __forceinline__ float p_angle_f(int h, int i){
  return expf(((float)(h*64+i)) * (1.0f/512.0f) * logf(1e-4f));
}

// ------------------- f32 -> bf16 hi/lo split (RNE both) ----------------------
__device__ __forceinline__ u16 bf16_rne(float f){
  u32 u = __float_as_uint(f);
  u += 0x7fffu + ((u >> 16) & 1u);
  return (u16)(u >> 16);
}
__device__ __forceinline__ void split_bf16(float f, u16& h, u16& l){
  u32 u = __float_as_uint(f);
  u32 r = (u + 0x7fffu + ((u >> 16) & 1u)) >> 16;
  h = (u16)r;
  float d = f - __uint_as_float(r << 16);
  l = bf16_rne(d);
}

// async 16B global->LDS (lds dest wave-uniform; HW adds lane*16)
__device__ __forceinline__ void gload_lds16(const u16* g, u16* l){
  __builtin_amdgcn_global_load_lds(
      (const __attribute__((address_space(1))) u32*)(const void*)g,
      (__attribute__((address_space(3))) u32*)(void*)l, 16, 0, 0);
}

// ---------------- conversion pass: f32[n] -> bf16 hi[n], lo[n] ---------------
__global__ __launch_bounds__(256) void k_convert(const float* __restrict__ in,
                                                 u16* __restrict__ hi,
                                                 u16* __restrict__ lo, int n){
  int i = (blockIdx.x*256 + threadIdx.x)*4;
  if (i >= n) return;
  float4 v = *(const float4*)(in + i);
  ushort4 h, l;
  split_bf16(v.x, h.x, l.x);
  split_bf16(v.y, h.y, l.y);
  split_bf16(v.z, h.z, l.z);
  split_bf16(v.w, h.w, l.w);
  *(ushort4*)(hi + i) = h;
  *(ushort4*)(lo + i) = l;
}

// ---------------- split-bf16 MFMA GEMM, dbuf + global_load_lds ---------------
template<int BM, int BN>
__global__ __launch_bounds__(256, 2) void k_gemm_bs(
    const u16* __restrict__ Ahg, const u16* __restrict__ Alg,
    const u16* __restrict__ Bhg, const u16* __restrict__ Blg,
    const float* __restrict__ bias0, const float* __restrict__ bias1, int nsplit,
    float* __restrict__ C0, float* __restrict__ C1, int ldc0, int ldc1,
    int M, int N, int K){
  constexpr int MI = BM/32, NJ = BN/32;
  constexpr int NIA = BM/16, NIB = BN/16;
  constexpr int TOTIS = 2*NIA + 2*NIB;
  constexpr int LA = BM*32;
  constexpr int LB = BN*32;
  __shared__ __align__(16) u16 lds[2][2*LA + 2*LB];
  int tid = threadIdx.x;
  int m0 = blockIdx.y * BM, n0 = blockIdx.x * BN;
  int wid = tid >> 6, lane = tid & 63;
  int wr = wid >> 1, wc = wid & 1;
  int fr = lane & 15, fq = lane >> 4;

  f32x4 acc[MI][NJ];
  #pragma unroll
  for (int mi = 0; mi < MI; mi++)
    #pragma unroll
    for (int nj = 0; nj < NJ; nj++)
      acc[mi][nj] = (f32x4){0.f, 0.f, 0.f, 0.f};

  int rlane = lane >> 2, slane = lane & 3;

  auto STAGE = [&](int buf, int k0){
    u16* L = &lds[buf][0];
    #pragma unroll
    for (int uu = 0; uu < TOTIS/4; uu++){
      int u = uu*4 + wid;
      int q; const u16* src; int lbase;
      if (u < NIA)            { q = u;              src = Ahg + (size_t)m0*K; lbase = 0; }
      else if (u < 2*NIA)     { q = u - NIA;        src = Alg + (size_t)m0*K; lbase = LA; }
      else if (u < 2*NIA+NIB) { q = u - 2*NIA;      src = Bhg + (size_t)n0*K; lbase = 2*LA; }
      else                    { q = u - 2*NIA-NIB;  src = Blg + (size_t)n0*K; lbase = 2*LA + LB; }
      int rl = q*16 + rlane;
      int colel = ((slane ^ ((rl>>1)&3)))*8;
      gload_lds16(src + (size_t)rl*K + k0 + colel, L + lbase + q*512);
    }
  };

  int NT = K/32;
  STAGE(0, 0);
  __syncthreads();
  int cur = 0;
  for (int t = 0; t < NT; t++){
    if (t+1 < NT) STAGE(cur^1, (t+1)*32);
    const u16* L = &lds[cur][0];
    b16x8 ah[MI], al[MI], bh[NJ], bl[NJ];
    #pragma unroll
    for (int mi = 0; mi < MI; mi++){
      int r = wr*(BM/2) + mi*16 + fr;
      int c = (fq ^ ((r>>1)&3))*8;
      ah[mi] = *(const b16x8*)(L + r*32 + c);
      al[mi] = *(const b16x8*)(L + LA + r*32 + c);
    }
    #pragma unroll
    for (int nj = 0; nj < NJ; nj++){
      int r = wc*(BN/2) + nj*16 + fr;
      int c = (fq ^ ((r>>1)&3))*8;
      bh[nj] = *(const b16x8*)(L + 2*LA + r*32 + c);
      bl[nj] = *(const b16x8*)(L + 2*LA + LB + r*32 + c);
    }
    #pragma unroll
    for (int mi = 0; mi < MI; mi++)
      #pragma unroll
      for (int nj = 0; nj < NJ; nj++){
        acc[mi][nj] = __builtin_amdgcn_mfma_f32_16x16x32_bf16(ah[mi], bh[nj], acc[mi][nj], 0, 0, 0);
        acc[mi][nj] = __builtin_amdgcn_mfma_f32_16x16x32_bf16(ah[mi], bl[nj], acc[mi][nj], 0, 0, 0);
        acc[mi][nj] = __builtin_amdgcn_mfma_f32_16x16x32_bf16(al[mi], bh[nj], acc[mi][nj], 0, 0, 0);
      }
    __syncthreads();
    cur ^= 1;
  }

  int isC0 = (n0 < nsplit);
  float* Cp = isC0 ? C0 : C1;
  const float* bp = isC0 ? bias0 : bias1;
  int ld = isC0 ? ldc0 : ldc1;
  int nb = isC0 ? n0 : (n0 - nsplit);
  #pragma unroll
  for (int mi = 0; mi < MI; mi++)
    #pragma unroll
    for (int nj = 0; nj < NJ; nj++){
      int n = nb + wc*(BN/2) + nj*16 + fr;
      float bn = bp[n];
      #pragma unroll
      for (int r = 0; r < 4; r++){
        int m = m0 + wr*(BM/2) + mi*16 + fq*4 + r;
        Cp[(size_t)m*ld + n] = acc[mi][nj][r] + bn;
      }
    }
}

// ---------------- small projections: a_angle, ln_a_abs, scale_qk -------------
__global__ __launch_bounds__(256) void k_small_proj(
    const float* __restrict__ x,
    const float* __restrict__ W_aang, const float* __restrict__ b_aang,
    const float* __restrict__ W_lnabs, const float* __restrict__ b_lnabs,
    const float* __restrict__ W_pscale, const float* __restrict__ b_pscale,
    float* __restrict__ lnA, float* __restrict__ scaleq){
  int bl = blockIdx.x;
  int tid = threadIdx.x;
  const float* xr = x + (size_t)bl*1024;
  float part[24];
  #pragma unroll
  for (int r = 0; r < 24; r++) part[r] = 0.f;
  for (int k = tid; k < 1024; k += 256){
    float xv = xr[k];
    #pragma unroll
    for (int h = 0; h < 8; h++){
      part[h]    = fmaf(xv, W_aang  [h*1024+k], part[h]);
      part[8+h]  = fmaf(xv, W_lnabs [h*1024+k], part[8+h]);
      part[16+h] = fmaf(xv, W_pscale[h*1024+k], part[16+h]);
    }
  }
  __shared__ float red[24][4];
  int lane = tid & 63, wv = tid >> 6;
  #pragma unroll
  for (int r = 0; r < 24; r++){
    float s = part[r];
    #pragma unroll
    for (int off = 32; off >= 1; off >>= 1) s += __shfl_down(s, off);
    if (lane == 0) red[r][wv] = s;
  }
  __syncthreads();
  if (tid < 24){
    red[tid][0] = red[tid][0] + red[tid][1] + red[tid][2] + red[tid][3];
  }
  __syncthreads();
  if (tid < 8){
    int h = tid;
    float aang  = tanhf(red[h][0] + b_aang[h]);
    float lnabs = -expf(red[8+h][0] + b_lnabs[h]);
    float scv   = red[16+h][0] + b_pscale[h];
    float sc    = -1.f / (1.f + expf(-scv));
    float pa0   = p_angle_f(h, 0);
    lnA[(bl*8+h)*2+0] = lnabs * pa0;
    lnA[(bl*8+h)*2+1] = aang  * pa0;
    scaleq[bl*8+h] = sc;
  }
}

// ---------------- inclusive cumsum of ln_a over L per (b,h) ------------------
__global__ void k_cumsum(const float* __restrict__ lnA, float* __restrict__ Aout){
  int bh = blockIdx.x; int b = bh >> 3, h = bh & 7;
  __shared__ float2 buf[2][LSEQ];
  int l = threadIdx.x;
  float2 v;
  v.x = lnA[(((size_t)b*LSEQ + l)*8 + h)*2 + 0];
  v.y = lnA[(((size_t)b*LSEQ + l)*8 + h)*2 + 1];
  buf[0][l] = v;
  __syncthreads();
  int src = 0;
  for (int off = 1; off < LSEQ; off <<= 1){
    float2 w = buf[src][l];
    if (l >= off){ float2 u = buf[src][l-off]; w.x += u.x; w.y += u.y; }
    buf[src^1][l] = w;
    __syncthreads();
    src ^= 1;
  }
  float2 r = buf[src][l];
  ((float2*)Aout)[(size_t)bh*LSEQ + l] = r;
}

// ---------------- t -> qp, kp, v ([BH][L][I] float2) -------------------------
__global__ __launch_bounds__(256) void k_transform(
    const float* __restrict__ t, const float* __restrict__ scaleq,
    float* __restrict__ qp, float* __restrict__ kp, float* __restrict__ v){
  int bl = blockIdx.x; int b = bl >> 10, l = bl & 1023;
  int tid = threadIdx.x;
  const float* tr = t + (size_t)bl*3072;
  float lnSc = logf(1024.f) - logf(32.f);
  for (int p = tid; p < 512; p += 256){
    int h = p >> 6, i = p & 63;
    const float2* tf = (const float2*)(tr + h*384 + i*6);
    float2 q  = tf[0];
    float2 kk = tf[1];
    float2 vv = tf[2];
    float sq_ = 1.f/(1.f + sqrtf(q.x*q.x + q.y*q.y));   q.x*=sq_; q.y*=sq_;
    float sk_ = 1.f/(1.f + sqrtf(kk.x*kk.x + kk.y*kk.y)); kk.x*=sk_; kk.y*=sk_;
    float sv_ = 1.f/(1.f + sqrtf(vv.x*vv.x + vv.y*vv.y)); vv.x*=sv_; vv.y*=sv_;
    float pa  = p_angle_f(h, i);
    float pas = expf(logf(32.f) + ((float)h)*(1.f/7.f)*lnSc);
    float sc  = scaleq[bl*8+h];
    float diff = sc * pas * pa;
    float phase = pa * (float)l;
    float aq, ak;
    if ((i & 1) == 0){ aq = phase + diff; ak = -phase; }
    else             { aq = phase;        ak = -phase + diff; }
    float s1, c1; sincosf(aq, &s1, &c1);
    float s2, c2; sincosf(ak, &s2, &c2);
    float2 qpv = cmul(q,  make_float2(c1, s1));
    float2 kpv = cmul(kk, make_float2(c2, s2));
    size_t idx = (((size_t)(b*8+h))*LSEQ + l)*64 + i;
    ((float2*)qp)[idx] = qpv;
    ((float2*)kp)[idx] = kpv;
    ((float2*)v )[idx] = vv;
  }
}

// ---------------- per-chunk KV state T_c (stored transposed [j][i]) ----------
__global__ __launch_bounds__(256) void k_chunkT(
    const float* __restrict__ kp, const float* __restrict__ v,
    const float* __restrict__ A, float* __restrict__ T){
  int blk = blockIdx.x;
  int bh = blk >> 4, c = blk & 15;
  int l0 = c*CHK;
  __shared__ float2 kpS[64][65];
  __shared__ float2 vS [64][65];
  __shared__ float2 wS [64];
  int tid = threadIdx.x;
  const float2* kpg = (const float2*)kp + ((size_t)bh*LSEQ + l0)*64;
  const float2* vg  = (const float2*)v  + ((size_t)bh*LSEQ + l0)*64;
  for (int e = tid; e < 4096; e += 256){
    kpS[e>>6][e&63] = kpg[e];
    vS [e>>6][e&63] = vg [e];
  }
  const float2* Ag = (const float2*)A + (size_t)bh*LSEQ;
  if (tid < 64){
    float2 Aend = Ag[l0+63];
    float2 Am   = Ag[l0+tid];
    wS[tid] = cexpf2(make_float2(Aend.x - Am.x, Aend.y - Am.y));
  }
  __syncthreads();
  int i = tid & 63, jg = tid >> 6;
  float2 acc[16];
  #pragma unroll
  for (int jj = 0; jj < 16; jj++) acc[jj] = make_float2(0.f, 0.f);
  for (int m = 0; m < 64; m++){
    float2 wkp = cmul(wS[m], kpS[m][i]);
    #pragma unroll
    for (int jj = 0; jj < 16; jj++)
      acc[jj] = cfma(wkp, vS[m][jg*16+jj], acc[jj]);
  }
  float2* Tg = (float2*)T + (size_t)blk*4096;
  #pragma unroll
  for (int jj = 0; jj < 16; jj++)
    Tg[(jg*16+jj)*64 + i] = acc[jj];
}

// ------- parallel chunk-state reconstruction (replaces serial scan) ----------
// S_states[c] = exp(D_c) S_init + sum_{c'<c} exp(D_c - E_{c'}) T_{c'},
//   D_c = A[c*64-1] (0 for c=0), E_{c'} = A[c'*64+63]. c==16 block -> hidden_next.
__global__ __launch_bounds__(256) void k_states(
    const float* __restrict__ hidden_r, const float* __restrict__ hidden_i,
    const float* __restrict__ A, const float* __restrict__ T,
    float* __restrict__ S_states, float* __restrict__ out_re,
    float* __restrict__ out_im, int write_imag){
  int blk = blockIdx.x;
  int bh = blk / 17, c = blk % 17;
  int h = bh & 7;
  int tid = threadIdx.x;
  const float2* Ag = (const float2*)A + (size_t)bh*LSEQ;
  __shared__ float2 wsh[17];
  float2 D = (c > 0) ? Ag[c*64 - 1] : make_float2(0.f, 0.f);
  if (tid < c){
    float2 E = Ag[tid*64 + 63];
    wsh[tid] = cexpf2(make_float2(D.x - E.x, D.y - E.y));
  }
  if (tid == 16) wsh[16] = cexpf2(D);
  __syncthreads();
  float2 winit = wsh[16];
  float2 acc[16];
  #pragma unroll
  for (int t = 0; t < 16; t++){
    int e = tid + 256*t;
    int j = e >> 6, i = e & 63;
    float pa = p_angle_f(h, i);
    float hr = hidden_r[(size_t)bh*4096 + i*64 + j];
    float hi = hidden_i[(size_t)bh*4096 + i*64 + j];
    float sn, cs; sincosf(pa, &sn, &cs);
    float2 si = cmul(make_float2(hr, hi), make_float2(cs, sn));
    acc[t] = cmul(winit, si);
  }
  for (int cp = 0; cp < c && cp < 16; cp++){
    float2 w = wsh[cp];
    const float2* Tg = (const float2*)T + ((size_t)bh*16 + cp)*4096;
    #pragma unroll
    for (int t = 0; t < 16; t++){
      float2 tv = Tg[tid + 256*t];
      acc[t] = cfma(w, tv, acc[t]);
    }
  }
  if (c < 16){
    float2* Sg = (float2*)S_states + ((size_t)bh*16 + c)*4096;
    #pragma unroll
    for (int t = 0; t < 16; t++) Sg[tid + 256*t] = acc[t];
  } else {
    #pragma unroll
    for (int t = 0; t < 16; t++){
      int e = tid + 256*t;
      int j = e >> 6, i = e & 63;
      float pa = p_angle_f(h, i);
      float sn, cs; sincosf(pa * (float)(LSEQ-1), &sn, &cs);
      float2 r = cmul(acc[t], make_float2(cs, sn));
      size_t o = (size_t)bh*4096 + i*64 + j;
      out_re[o] = r.x;
      if (write_imag) out_im[o] = r.y;
    }
  }
}

// ------- per-chunk attention, 2 blocks/chunk (32 rows each), 2 LDS bufs ------
__global__ __launch_bounds__(256) void k_attn(
    const float* __restrict__ qp, const float* __restrict__ kp,
    const float* __restrict__ v, const float* __restrict__ A,
    const float* __restrict__ S_states, float* __restrict__ hr_out){
  int blk = blockIdx.x;                  // ((bh*16)+c)*2 + half
  int bh = blk >> 5, c = (blk >> 1) & 15, half = blk & 1;
  int b = bh >> 3, h = bh & 7;
  int l0 = c*CHK;
  int rowbase = half*32;
  __shared__ float2 bufA[32][65];        // qp rows -> later qck
  __shared__ float2 bufB[64][65];        // S -> kp -> v
  __shared__ float2 dA[64];
  __shared__ float2 eD[64];
  int tid = threadIdx.x;
  const float2* qpg = (const float2*)qp + ((size_t)bh*LSEQ + l0 + rowbase)*64;
  for (int e = tid; e < 2048; e += 256) bufA[e>>6][e&63] = qpg[e];
  const float2* Sg = (const float2*)S_states + ((size_t)(bh*16 + c))*4096;
  for (int e = tid; e < 4096; e += 256) bufB[e>>6][e&63] = Sg[e];
  const float2* Ag = (const float2*)A + (size_t)bh*LSEQ;
  if (tid < 64){
    float2 As = (l0 > 0) ? Ag[l0-1] : make_float2(0.f, 0.f);
    float2 Al = Ag[l0+tid];
    float2 d = make_float2(Al.x - As.x, Al.y - As.y);
    dA[tid] = d;
    eD[tid] = cexpf2(d);
  }
  __syncthreads();

  int l = tid >> 3, jg = tid & 7;        // l: 0..31 local row, jg: 0..7
  int lr = rowbase + l;                  // row within chunk
  float2 hacc[8];
  #pragma unroll
  for (int jj = 0; jj < 8; jj++) hacc[jj] = make_float2(0.f, 0.f);

  // phase A: h_l[j] = (sum_i qp_l[i] * S[i][j]) * eD[lr]
  for (int i = 0; i < 64; i++){
    float2 qv = bufA[l][i];
    #pragma unroll
    for (int jj = 0; jj < 8; jj++)
      hacc[jj] = cfma(qv, bufB[jg + 8*jj][i], hacc[jj]);
  }
  {
    float2 ed = eD[lr];
    #pragma unroll
    for (int jj = 0; jj < 8; jj++) hacc[jj] = cmul(ed, hacc[jj]);
  }
  __syncthreads();
  // load kp over S
  const float2* kpg = (const float2*)kp + ((size_t)bh*LSEQ + l0)*64;
  for (int e = tid; e < 4096; e += 256) bufB[e>>6][e&63] = kpg[e];
  __syncthreads();

  // B1: qck[lr][m] = (sum_i qp_lr[i]*kp_m[i]) * exp(dA_lr - dA_m), m<=lr
  float2 qck[8];
  #pragma unroll
  for (int mm = 0; mm < 8; mm++) qck[mm] = make_float2(0.f, 0.f);
  for (int i = 0; i < 64; i++){
    float2 qv = bufA[l][i];
    #pragma unroll
    for (int mm = 0; mm < 8; mm++)
      qck[mm] = cfma(qv, bufB[jg + 8*mm][i], qck[mm]);
  }
  {
    float2 dl = dA[lr];
    #pragma unroll
    for (int mm = 0; mm < 8; mm++){
      int m = jg + 8*mm;
      float2 w = make_float2(0.f, 0.f);
      if (m <= lr){
        float2 dm = dA[m];
        w = cexpf2(make_float2(dl.x - dm.x, dl.y - dm.y));
      }
      qck[mm] = cmul(qck[mm], w);
    }
  }
  __syncthreads();                       // qp & kp reads complete
  // write qck into bufA; load v over kp
  #pragma unroll
  for (int mm = 0; mm < 8; mm++) bufA[l][jg + 8*mm] = qck[mm];
  const float2* vg = (const float2*)v + ((size_t)bh*LSEQ + l0)*64;
  for (int e = tid; e < 4096; e += 256) bufB[e>>6][e&63] = vg[e];
  __syncthreads();

  // B2: h_l[j] += sum_m qck[l][m] * v_m[j]
  for (int m = 0; m < 64; m++){
    float2 qc = bufA[l][m];
    #pragma unroll
    for (int jj = 0; jj < 8; jj++)
      hacc[jj] = cfma(qc, bufB[m][jg + 8*jj], hacc[jj]);
  }
  float2* out = (float2*)hr_out;
  size_t base = (((size_t)(b*LSEQ + l0 + lr))*8 + h)*64;
  #pragma unroll
  for (int jj = 0; jj < 8; jj++)
    out[base + jg + 8*jj] = hacc[jj];
}

// -------- GroupNorm * silu(g) -> bf16 hi/lo planes (fused conversion) --------
__global__ __launch_bounds__(256) void k_gn(
    const float* __restrict__ g, const float* __restrict__ hr,
    const float* __restrict__ gn_w, const float* __restrict__ gn_b,
    u16* __restrict__ hnh, u16* __restrict__ hnl){
  int bl = blockIdx.x;
  int tid = threadIdx.x;
  int h = tid >> 5, c32 = tid & 31;
  const float* hp = hr + ((size_t)bl*8 + h)*128 + c32*4;
  const float* gp = g + (size_t)bl*1024 + h*128 + c32*4;
  float4 v = *(const float4*)hp;
  float s = v.x + v.y + v.z + v.w;
  #pragma unroll
  for (int off = 16; off >= 1; off >>= 1) s += __shfl_xor(s, off);
  float mean = s * (1.f/128.f);
  float dx = v.x - mean, dy = v.y - mean, dz = v.z - mean, dw = v.w - mean;
  float ss = dx*dx + dy*dy + dz*dz + dw*dw;
  #pragma unroll
  for (int off = 16; off >= 1; off >>= 1) ss += __shfl_xor(ss, off);
  float inv = rsqrtf(ss * (1.f/128.f) + 1e-5f);
  float w = gn_w[h] * inv, bb = gn_b[h];
  float4 gv = *(const float4*)gp;
  float4 o;
  o.x = (dx*w + bb) * (gv.x / (1.f + expf(-gv.x)));
  o.y = (dy*w + bb) * (gv.y / (1.f + expf(-gv.y)));
  o.z = (dz*w + bb) * (gv.z / (1.f + expf(-gv.z)));
  o.w = (dw*w + bb) * (gv.w / (1.f + expf(-gv.w)));
  ushort4 oh, ol;
  split_bf16(o.x, oh.x, ol.x);
  split_bf16(o.y, oh.y, ol.y);
  split_bf16(o.z, oh.z, ol.z);
  split_bf16(o.w, oh.w, ol.w);
  size_t idx = (size_t)bl*1024 + h*128 + c32*4;
  *(ushort4*)(hnh + idx) = oh;
  *(ushort4*)(hnl + idx) = ol;
}

extern "C" void kernel_launch(void* const* d_in, const int* in_sizes, int n_in,
                              void* d_out, int out_size, void* d_ws, size_t ws_size,
                              hipStream_t stream) {
  const float* x        = (const float*)d_in[0];
  const float* hidden_r = (const float*)d_in[1];
  const float* hidden_i = (const float*)d_in[2];
  const float* W_qkv    = (const float*)d_in[3];
  const float* b_qkv    = (const float*)d_in[4];
  const float* W_g      = (const float*)d_in[5];
  const float* b_g      = (const float*)d_in[6];
  const float* W_aang   = (const float*)d_in[7];
  const float* b_aang   = (const float*)d_in[8];
  const float* W_lnabs  = (const float*)d_in[9];
  const float* b_lnabs  = (const float*)d_in[10];
  const float* W_pscale = (const float*)d_in[11];
  const float* b_pscale = (const float*)d_in[12];
  const float* W_y      = (const float*)d_in[13];
  const float* b_y      = (const float*)d_in[14];
  const float* gn_w     = (const float*)d_in[15];
  const float* gn_b     = (const float*)d_in[16];

  float* ws = (float*)d_ws;
  float* t_buf  = ws;
  float* hr_buf = t_buf;
  float* T_buf  = t_buf + 2097152;
  float* S_buf  = t_buf + 4194304;
  u16*   hnh    = (u16*)(t_buf + 2097152);
  u16*   hnl    = (u16*)(t_buf + 2097152) + 2097152;
  float* g_buf  = ws + 6291456;
  u16*   Wch    = (u16*)(ws + 8388608);
  u16*   Wcl    = Wch + 4194304;
  float* qp_buf = ws + 8388608;
  float* kp_buf = ws + 10485760;
  u16*   xh     = (u16*)(ws + 12582912);
  u16*   xl     = xh + 2097152;
  float* v_buf  = ws + 12582912;
  u16*   Wyh    = (u16*)(ws + 14680064);
  u16*   Wyl    = Wyh + 1048576;
  float* lnA    = ws + 15728640;
  float* scaleq = lnA + 32768;
  float* A_buf  = scaleq + 16384;

  float* y_out  = (float*)d_out;
  float* hid_re = (float*)d_out + 2097152;
  float* hid_im = (float*)d_out + 2097152 + 65536;
  int write_imag = (out_size >= 2097152 + 2*65536) ? 1 : 0;

  // 0) conversions
  k_convert<<<2048, 256, 0, stream>>>(x, xh, xl, 2097152);
  k_convert<<<3072, 256, 0, stream>>>(W_qkv, Wch, Wcl, 3145728);
  k_convert<<<1024, 256, 0, stream>>>(W_g, Wch + 3145728, Wcl + 3145728, 1048576);
  k_convert<<<1024, 256, 0, stream>>>(W_y, Wyh, Wyl, 1048576);

  // 1) fused [t|g] = x @ [W_qkv;W_g]^T + bias
  k_gemm_bs<128,128><<<dim3(4096/128, 2048/128), 256, 0, stream>>>(
      xh, xl, Wch, Wcl, b_qkv, b_g, 3072, t_buf, g_buf, 3072, 1024, 2048, 4096, 1024);
  // 2) small projections
  k_small_proj<<<2048, 256, 0, stream>>>(x, W_aang, b_aang, W_lnabs, b_lnabs, W_pscale, b_pscale, lnA, scaleq);
  // 3) cumsum
  k_cumsum<<<16, 1024, 0, stream>>>(lnA, A_buf);
  // 4) t -> qp, kp, v
  k_transform<<<2048, 256, 0, stream>>>(t_buf, scaleq, qp_buf, kp_buf, v_buf);
  // 5) per-chunk KV states
  k_chunkT<<<256, 256, 0, stream>>>(kp_buf, v_buf, A_buf, T_buf);
  // 6) parallel state reconstruction + hidden_next (272 blocks)
  k_states<<<272, 256, 0, stream>>>(hidden_r, hidden_i, A_buf, T_buf, S_buf, hid_re, hid_im, write_imag);
  // 7) per-chunk attention, 2 blocks per chunk
  k_attn<<<512, 256, 0, stream>>>(qp_buf, kp_buf, v_buf, A_buf, S_buf, hr_buf);
  // 8) GroupNorm * silu(g) -> bf16 hi/lo
  k_gn<<<2048, 256, 0, stream>>>(g_buf, hr_buf, gn_w, gn_b, hnh, hnl);
  // 9) y = hn @ W_y^T + b_y
  k_gemm_bs<64,64><<<dim3(1024/64, 2048/64), 256, 0, stream>>>(
      hnh, hnl, Wyh, Wyl, b_y, b_y, 1024, y_out, y_out, 1024, 1024, 2048, 1024, 1024);
}

// Round 7
// 276.005 us; speedup vs baseline: 1.2532x; 1.2532x over previous
//
#include <hip/hip_runtime.h>
#include <math.h>

// SioConvLayer fused forward, MI355X (r7).
// r6: 345.9us, REGRESSION from k_states (76us, latency-bound: 1 wave/SIMD,
// serial dependent chunk-walk). r7: k_states rewritten as element-parallel
// weighted sum: 1 element/thread (65536 threads), all 16 T loads issued
// up-front, 17 outputs computed from registers (136 cfma, 1 live acc).
// Weights w_T[c][cp]=exp(D_c - D_{cp+1}) precomputed in LDS; algebraically
// identical to the validated serial recurrence. All other kernels byte-identical to r6.

#define LSEQ 1024
#define NCHUNK 16
#define CHK 64

typedef float2 cf;
typedef unsigned short u16;
typedef unsigned int u32;
typedef __bf16 b16x8 __attribute__((ext_vector_type(8)));
typedef float f32x4 __attribute__((ext_vector_type(4)));

__device__ __forceinline__ cf cmul(cf a, cf b){
  return make_float2(a.x*b.x - a.y*b.y, a.x*b.y + a.y*b.x);
}
__device__ __forceinline__ cf cfma(cf a, cf b, cf c){
  c.x = fmaf(a.x, b.x, fmaf(-a.y, b.y, c.x));
  c.y = fmaf(a.x, b.y, fmaf( a.y, b.x, c.y));
  return c;
}
__device__ __forceinline__ cf cexpf2(cf a){
  float e = expf(a.x); float s, c; sincosf(a.y, &s, &c);
  return make_float2(e*c, e*s);
}
__device__ __forceinline__ float p_angle_f(int h, int i){
  return expf(((float)(h*64+i)) * (1.0f/512.0f) * logf(1e-4f));
}

// ------------------- f32 -> bf16 hi/lo split (RNE both) ----------------------
__device__ __forceinline__ u16 bf16_rne(float f){
  u32 u = __float_as_uint(f);
  u += 0x7fffu + ((u >> 16) & 1u);
  return (u16)(u >> 16);
}
__device__ __forceinline__ void split_bf16(float f, u16& h, u16& l){
  u32 u = __float_as_uint(f);
  u32 r = (u + 0x7fffu + ((u >> 16) & 1u)) >> 16;
  h = (u16)r;
  float d = f - __uint_as_float(r << 16);
  l = bf16_rne(d);
}

// async 16B global->LDS (lds dest wave-uniform; HW adds lane*16)
__device__ __forceinline__ void gload_lds16(const u16* g, u16* l){
  __builtin_amdgcn_global_load_lds(
      (const __attribute__((address_space(1))) u32*)(const void*)g,
      (__attribute__((address_space(3))) u32*)(void*)l, 16, 0, 0);
}

// ---------------- conversion pass: f32[n] -> bf16 hi[n], lo[n] ---------------
__global__ __launch_bounds__(256) void k_convert(const float* __restrict__ in,
                                                 u16* __restrict__ hi,
                                                 u16* __restrict__ lo, int n){
  int i = (blockIdx.x*256 + threadIdx.x)*4;
  if (i >= n) return;
  float4 v = *(const float4*)(in + i);
  ushort4 h, l;
  split_bf16(v.x, h.x, l.x);
  split_bf16(v.y, h.y, l.y);
  split_bf16(v.z, h.z, l.z);
  split_bf16(v.w, h.w, l.w);
  *(ushort4*)(hi + i) = h;
  *(ushort4*)(lo + i) = l;
}

// ---------------- split-bf16 MFMA GEMM, dbuf + global_load_lds ---------------
template<int BM, int BN>
__global__ __launch_bounds__(256, 2) void k_gemm_bs(
    const u16* __restrict__ Ahg, const u16* __restrict__ Alg,
    const u16* __restrict__ Bhg, const u16* __restrict__ Blg,
    const float* __restrict__ bias0, const float* __restrict__ bias1, int nsplit,
    float* __restrict__ C0, float* __restrict__ C1, int ldc0, int ldc1,
    int M, int N, int K){
  constexpr int MI = BM/32, NJ = BN/32;
  constexpr int NIA = BM/16, NIB = BN/16;
  constexpr int TOTIS = 2*NIA + 2*NIB;
  constexpr int LA = BM*32;
  constexpr int LB = BN*32;
  __shared__ __align__(16) u16 lds[2][2*LA + 2*LB];
  int tid = threadIdx.x;
  int m0 = blockIdx.y * BM, n0 = blockIdx.x * BN;
  int wid = tid >> 6, lane = tid & 63;
  int wr = wid >> 1, wc = wid & 1;
  int fr = lane & 15, fq = lane >> 4;

  f32x4 acc[MI][NJ];
  #pragma unroll
  for (int mi = 0; mi < MI; mi++)
    #pragma unroll
    for (int nj = 0; nj < NJ; nj++)
      acc[mi][nj] = (f32x4){0.f, 0.f, 0.f, 0.f};

  int rlane = lane >> 2, slane = lane & 3;

  auto STAGE = [&](int buf, int k0){
    u16* L = &lds[buf][0];
    #pragma unroll
    for (int uu = 0; uu < TOTIS/4; uu++){
      int u = uu*4 + wid;
      int q; const u16* src; int lbase;
      if (u < NIA)            { q = u;              src = Ahg + (size_t)m0*K; lbase = 0; }
      else if (u < 2*NIA)     { q = u - NIA;        src = Alg + (size_t)m0*K; lbase = LA; }
      else if (u < 2*NIA+NIB) { q = u - 2*NIA;      src = Bhg + (size_t)n0*K; lbase = 2*LA; }
      else                    { q = u - 2*NIA-NIB;  src = Blg + (size_t)n0*K; lbase = 2*LA + LB; }
      int rl = q*16 + rlane;
      int colel = ((slane ^ ((rl>>1)&3)))*8;
      gload_lds16(src + (size_t)rl*K + k0 + colel, L + lbase + q*512);
    }
  };

  int NT = K/32;
  STAGE(0, 0);
  __syncthreads();
  int cur = 0;
  for (int t = 0; t < NT; t++){
    if (t+1 < NT) STAGE(cur^1, (t+1)*32);
    const u16* L = &lds[cur][0];
    b16x8 ah[MI], al[MI], bh[NJ], bl[NJ];
    #pragma unroll
    for (int mi = 0; mi < MI; mi++){
      int r = wr*(BM/2) + mi*16 + fr;
      int c = (fq ^ ((r>>1)&3))*8;
      ah[mi] = *(const b16x8*)(L + r*32 + c);
      al[mi] = *(const b16x8*)(L + LA + r*32 + c);
    }
    #pragma unroll
    for (int nj = 0; nj < NJ; nj++){
      int r = wc*(BN/2) + nj*16 + fr;
      int c = (fq ^ ((r>>1)&3))*8;
      bh[nj] = *(const b16x8*)(L + 2*LA + r*32 + c);
      bl[nj] = *(const b16x8*)(L + 2*LA + LB + r*32 + c);
    }
    #pragma unroll
    for (int mi = 0; mi < MI; mi++)
      #pragma unroll
      for (int nj = 0; nj < NJ; nj++){
        acc[mi][nj] = __builtin_amdgcn_mfma_f32_16x16x32_bf16(ah[mi], bh[nj], acc[mi][nj], 0, 0, 0);
        acc[mi][nj] = __builtin_amdgcn_mfma_f32_16x16x32_bf16(ah[mi], bl[nj], acc[mi][nj], 0, 0, 0);
        acc[mi][nj] = __builtin_amdgcn_mfma_f32_16x16x32_bf16(al[mi], bh[nj], acc[mi][nj], 0, 0, 0);
      }
    __syncthreads();
    cur ^= 1;
  }

  int isC0 = (n0 < nsplit);
  float* Cp = isC0 ? C0 : C1;
  const float* bp = isC0 ? bias0 : bias1;
  int ld = isC0 ? ldc0 : ldc1;
  int nb = isC0 ? n0 : (n0 - nsplit);
  #pragma unroll
  for (int mi = 0; mi < MI; mi++)
    #pragma unroll
    for (int nj = 0; nj < NJ; nj++){
      int n = nb + wc*(BN/2) + nj*16 + fr;
      float bn = bp[n];
      #pragma unroll
      for (int r = 0; r < 4; r++){
        int m = m0 + wr*(BM/2) + mi*16 + fq*4 + r;
        Cp[(size_t)m*ld + n] = acc[mi][nj][r] + bn;
      }
    }
}

// ---------------- small projections: a_angle, ln_a_abs, scale_qk -------------
__global__ __launch_bounds__(256) void k_small_proj(
    const float* __restrict__ x,
    const float* __restrict__ W_aang, const float* __restrict__ b_aang,
    const float* __restrict__ W_lnabs, const float* __restrict__ b_lnabs,
    const float* __restrict__ W_pscale, const float* __restrict__ b_pscale,
    float* __restrict__ lnA, float* __restrict__ scaleq){
  int bl = blockIdx.x;
  int tid = threadIdx.x;
  const float* xr = x + (size_t)bl*1024;
  float part[24];
  #pragma unroll
  for (int r = 0; r < 24; r++) part[r] = 0.f;
  for (int k = tid; k < 1024; k += 256){
    float xv = xr[k];
    #pragma unroll
    for (int h = 0; h < 8; h++){
      part[h]    = fmaf(xv, W_aang  [h*1024+k], part[h]);
      part[8+h]  = fmaf(xv, W_lnabs [h*1024+k], part[8+h]);
      part[16+h] = fmaf(xv, W_pscale[h*1024+k], part[16+h]);
    }
  }
  __shared__ float red[24][4];
  int lane = tid & 63, wv = tid >> 6;
  #pragma unroll
  for (int r = 0; r < 24; r++){
    float s = part[r];
    #pragma unroll
    for (int off = 32; off >= 1; off >>= 1) s += __shfl_down(s, off);
    if (lane == 0) red[r][wv] = s;
  }
  __syncthreads();
  if (tid < 24){
    red[tid][0] = red[tid][0] + red[tid][1] + red[tid][2] + red[tid][3];
  }
  __syncthreads();
  if (tid < 8){
    int h = tid;
    float aang  = tanhf(red[h][0] + b_aang[h]);
    float lnabs = -expf(red[8+h][0] + b_lnabs[h]);
    float scv   = red[16+h][0] + b_pscale[h];
    float sc    = -1.f / (1.f + expf(-scv));
    float pa0   = p_angle_f(h, 0);
    lnA[(bl*8+h)*2+0] = lnabs * pa0;
    lnA[(bl*8+h)*2+1] = aang  * pa0;
    scaleq[bl*8+h] = sc;
  }
}

// ---------------- inclusive cumsum of ln_a over L per (b,h) ------------------
__global__ void k_cumsum(const float* __restrict__ lnA, float* __restrict__ Aout){
  int bh = blockIdx.x; int b = bh >> 3, h = bh & 7;
  __shared__ float2 buf[2][LSEQ];
  int l = threadIdx.x;
  float2 v;
  v.x = lnA[(((size_t)b*LSEQ + l)*8 + h)*2 + 0];
  v.y = lnA[(((size_t)b*LSEQ + l)*8 + h)*2 + 1];
  buf[0][l] = v;
  __syncthreads();
  int src = 0;
  for (int off = 1; off < LSEQ; off <<= 1){
    float2 w = buf[src][l];
    if (l >= off){ float2 u = buf[src][l-off]; w.x += u.x; w.y += u.y; }
    buf[src^1][l] = w;
    __syncthreads();
    src ^= 1;
  }
  float2 r = buf[src][l];
  ((float2*)Aout)[(size_t)bh*LSEQ + l] = r;
}

// ---------------- t -> qp, kp, v ([BH][L][I] float2) -------------------------
__global__ __launch_bounds__(256) void k_transform(
    const float* __restrict__ t, const float* __restrict__ scaleq,
    float* __restrict__ qp, float* __restrict__ kp, float* __restrict__ v){
  int bl = blockIdx.x; int b = bl >> 10, l = bl & 1023;
  int tid = threadIdx.x;
  const float* tr = t + (size_t)bl*3072;
  float lnSc = logf(1024.f) - logf(32.f);
  for (int p = tid; p < 512; p += 256){
    int h = p >> 6, i = p & 63;
    const float2* tf = (const float2*)(tr + h*384 + i*6);
    float2 q  = tf[0];
    float2 kk = tf[1];
    float2 vv = tf[2];
    float sq_ = 1.f/(1.f + sqrtf(q.x*q.x + q.y*q.y));   q.x*=sq_; q.y*=sq_;
    float sk_ = 1.f/(1.f + sqrtf(kk.x*kk.x + kk.y*kk.y)); kk.x*=sk_; kk.y*=sk_;
    float sv_ = 1.f/(1.f + sqrtf(vv.x*vv.x + vv.y*vv.y)); vv.x*=sv_; vv.y*=sv_;
    float pa  = p_angle_f(h, i);
    float pas = expf(logf(32.f) + ((float)h)*(1.f/7.f)*lnSc);
    float sc  = scaleq[bl*8+h];
    float diff = sc * pas * pa;
    float phase = pa * (float)l;
    float aq, ak;
    if ((i & 1) == 0){ aq = phase + diff; ak = -phase; }
    else             { aq = phase;        ak = -phase + diff; }
    float s1, c1; sincosf(aq, &s1, &c1);
    float s2, c2; sincosf(ak, &s2, &c2);
    float2 qpv = cmul(q,  make_float2(c1, s1));
    float2 kpv = cmul(kk, make_float2(c2, s2));
    size_t idx = (((size_t)(b*8+h))*LSEQ + l)*64 + i;
    ((float2*)qp)[idx] = qpv;
    ((float2*)kp)[idx] = kpv;
    ((float2*)v )[idx] = vv;
  }
}

// ---------------- per-chunk KV state T_c (stored transposed [j][i]) ----------
__global__ __launch_bounds__(256) void k_chunkT(
    const float* __restrict__ kp, const float* __restrict__ v,
    const float* __restrict__ A, float* __restrict__ T){
  int blk = blockIdx.x;
  int bh = blk >> 4, c = blk & 15;
  int l0 = c*CHK;
  __shared__ float2 kpS[64][65];
  __shared__ float2 vS [64][65];
  __shared__ float2 wS [64];
  int tid = threadIdx.x;
  const float2* kpg = (const float2*)kp + ((size_t)bh*LSEQ + l0)*64;
  const float2* vg  = (const float2*)v  + ((size_t)bh*LSEQ + l0)*64;
  for (int e = tid; e < 4096; e += 256){
    kpS[e>>6][e&63] = kpg[e];
    vS [e>>6][e&63] = vg [e];
  }
  const float2* Ag = (const float2*)A + (size_t)bh*LSEQ;
  if (tid < 64){
    float2 Aend = Ag[l0+63];
    float2 Am   = Ag[l0+tid];
    wS[tid] = cexpf2(make_float2(Aend.x - Am.x, Aend.y - Am.y));
  }
  __syncthreads();
  int i = tid & 63, jg = tid >> 6;
  float2 acc[16];
  #pragma unroll
  for (int jj = 0; jj < 16; jj++) acc[jj] = make_float2(0.f, 0.f);
  for (int m = 0; m < 64; m++){
    float2 wkp = cmul(wS[m], kpS[m][i]);
    #pragma unroll
    for (int jj = 0; jj < 16; jj++)
      acc[jj] = cfma(wkp, vS[m][jg*16+jj], acc[jj]);
  }
  float2* Tg = (float2*)T + (size_t)blk*4096;
  #pragma unroll
  for (int jj = 0; jj < 16; jj++)
    Tg[(jg*16+jj)*64 + i] = acc[jj];
}

// ------- element-parallel chunk-state reconstruction (r7) --------------------
// S_states[c][e] = w_init[c]*si[e] + sum_{cp<c} w_T[c][cp]*T[cp][e]
//   w_init[c] = exp(D_c), w_T[c][cp] = exp(D_c - D_{cp+1}),
//   D_0 = 0, D_c = A[c*64-1].  c==16 -> hidden_next (rotated).
// Grid: 256 blocks = 16 bh x 16 e-tiles of 256; 1 element/thread.
__global__ __launch_bounds__(256) void k_states(
    const float* __restrict__ hidden_r, const float* __restrict__ hidden_i,
    const float* __restrict__ A, const float* __restrict__ T,
    float* __restrict__ S_states, float* __restrict__ out_re,
    float* __restrict__ out_im, int write_imag){
  int bh = blockIdx.x >> 4;
  int e0 = (blockIdx.x & 15) * 256;
  int h = bh & 7;
  int tid = threadIdx.x;
  int e = e0 + tid;
  const float2* Ag = (const float2*)A + (size_t)bh*LSEQ;
  __shared__ float2 Dsh[17];
  __shared__ float2 wT[17][16];
  __shared__ float2 wI[17];
  if (tid < 17)
    Dsh[tid] = (tid > 0) ? Ag[tid*64 - 1] : make_float2(0.f, 0.f);
  __syncthreads();
  if (tid < 17) wI[tid] = cexpf2(Dsh[tid]);
  for (int idx = tid; idx < 17*16; idx += 256){
    int c = idx >> 4, cp = idx & 15;
    if (cp < c){
      float2 d = make_float2(Dsh[c].x - Dsh[cp+1].x, Dsh[c].y - Dsh[cp+1].y);
      wT[c][cp] = cexpf2(d);
    }
  }
  __syncthreads();

  // up-front independent loads
  float2 Tv[16];
  #pragma unroll
  for (int cp = 0; cp < 16; cp++)
    Tv[cp] = ((const float2*)T)[((size_t)bh*16 + cp)*4096 + e];
  int i = e & 63, j = e >> 6;
  float pa = p_angle_f(h, i);
  float hr = hidden_r[(size_t)bh*4096 + i*64 + j];
  float hi = hidden_i[(size_t)bh*4096 + i*64 + j];
  float sn, cs; sincosf(pa, &sn, &cs);
  float2 si = cmul(make_float2(hr, hi), make_float2(cs, sn));

  #pragma unroll
  for (int c = 0; c < 17; c++){
    float2 acc = cmul(wI[c], si);
    #pragma unroll
    for (int cp = 0; cp < 16; cp++){
      if (cp < c) acc = cfma(wT[c][cp], Tv[cp], acc);
    }
    if (c < 16){
      ((float2*)S_states)[((size_t)bh*16 + c)*4096 + e] = acc;
    } else {
      float sn2, cs2; sincosf(pa * (float)(LSEQ-1), &sn2, &cs2);
      float2 r = cmul(acc, make_float2(cs2, sn2));
      size_t o = (size_t)bh*4096 + i*64 + j;
      out_re[o] = r.x;
      if (write_imag) out_im[o] = r.y;
    }
  }
}

// ------- per-chunk attention, 2 blocks/chunk (32 rows each), 2 LDS bufs ------
__global__ __launch_bounds__(256) void k_attn(
    const float* __restrict__ qp, const float* __restrict__ kp,
    const float* __restrict__ v, const float* __restrict__ A,
    const float* __restrict__ S_states, float* __restrict__ hr_out){
  int blk = blockIdx.x;                  // ((bh*16)+c)*2 + half
  int bh = blk >> 5, c = (blk >> 1) & 15, half = blk & 1;
  int b = bh >> 3, h = bh & 7;
  int l0 = c*CHK;
  int rowbase = half*32;
  __shared__ float2 bufA[32][65];        // qp rows -> later qck
  __shared__ float2 bufB[64][65];        // S -> kp -> v
  __shared__ float2 dA[64];
  __shared__ float2 eD[64];
  int tid = threadIdx.x;
  const float2* qpg = (const float2*)qp + ((size_t)bh*LSEQ + l0 + rowbase)*64;
  for (int e = tid; e < 2048; e += 256) bufA[e>>6][e&63] = qpg[e];
  const float2* Sg = (const float2*)S_states + ((size_t)(bh*16 + c))*4096;
  for (int e = tid; e < 4096; e += 256) bufB[e>>6][e&63] = Sg[e];
  const float2* Ag = (const float2*)A + (size_t)bh*LSEQ;
  if (tid < 64){
    float2 As = (l0 > 0) ? Ag[l0-1] : make_float2(0.f, 0.f);
    float2 Al = Ag[l0+tid];
    float2 d = make_float2(Al.x - As.x, Al.y - As.y);
    dA[tid] = d;
    eD[tid] = cexpf2(d);
  }
  __syncthreads();

  int l = tid >> 3, jg = tid & 7;        // l: 0..31 local row, jg: 0..7
  int lr = rowbase + l;                  // row within chunk
  float2 hacc[8];
  #pragma unroll
  for (int jj = 0; jj < 8; jj++) hacc[jj] = make_float2(0.f, 0.f);

  // phase A: h_l[j] = (sum_i qp_l[i] * S[i][j]) * eD[lr]
  for (int i = 0; i < 64; i++){
    float2 qv = bufA[l][i];
    #pragma unroll
    for (int jj = 0; jj < 8; jj++)
      hacc[jj] = cfma(qv, bufB[jg + 8*jj][i], hacc[jj]);
  }
  {
    float2 ed = eD[lr];
    #pragma unroll
    for (int jj = 0; jj < 8; jj++) hacc[jj] = cmul(ed, hacc[jj]);
  }
  __syncthreads();
  // load kp over S
  const float2* kpg = (const float2*)kp + ((size_t)bh*LSEQ + l0)*64;
  for (int e = tid; e < 4096; e += 256) bufB[e>>6][e&63] = kpg[e];
  __syncthreads();

  // B1: qck[lr][m] = (sum_i qp_lr[i]*kp_m[i]) * exp(dA_lr - dA_m), m<=lr
  float2 qck[8];
  #pragma unroll
  for (int mm = 0; mm < 8; mm++) qck[mm] = make_float2(0.f, 0.f);
  for (int i = 0; i < 64; i++){
    float2 qv = bufA[l][i];
    #pragma unroll
    for (int mm = 0; mm < 8; mm++)
      qck[mm] = cfma(qv, bufB[jg + 8*mm][i], qck[mm]);
  }
  {
    float2 dl = dA[lr];
    #pragma unroll
    for (int mm = 0; mm < 8; mm++){
      int m = jg + 8*mm;
      float2 w = make_float2(0.f, 0.f);
      if (m <= lr){
        float2 dm = dA[m];
        w = cexpf2(make_float2(dl.x - dm.x, dl.y - dm.y));
      }
      qck[mm] = cmul(qck[mm], w);
    }
  }
  __syncthreads();                       // qp & kp reads complete
  // write qck into bufA; load v over kp
  #pragma unroll
  for (int mm = 0; mm < 8; mm++) bufA[l][jg + 8*mm] = qck[mm];
  const float2* vg = (const float2*)v + ((size_t)bh*LSEQ + l0)*64;
  for (int e = tid; e < 4096; e += 256) bufB[e>>6][e&63] = vg[e];
  __syncthreads();

  // B2: h_l[j] += sum_m qck[l][m] * v_m[j]
  for (int m = 0; m < 64; m++){
    float2 qc = bufA[l][m];
    #pragma unroll
    for (int jj = 0; jj < 8; jj++)
      hacc[jj] = cfma(qc, bufB[m][jg + 8*jj], hacc[jj]);
  }
  float2* out = (float2*)hr_out;
  size_t base = (((size_t)(b*LSEQ + l0 + lr))*8 + h)*64;
  #pragma unroll
  for (int jj = 0; jj < 8; jj++)
    out[base + jg + 8*jj] = hacc[jj];
}

// -------- GroupNorm * silu(g) -> bf16 hi/lo planes (fused conversion) --------
__global__ __launch_bounds__(256) void k_gn(
    const float* __restrict__ g, const float* __restrict__ hr,
    const float* __restrict__ gn_w, const float* __restrict__ gn_b,
    u16* __restrict__ hnh, u16* __restrict__ hnl){
  int bl = blockIdx.x;
  int tid = threadIdx.x;
  int h = tid >> 5, c32 = tid & 31;
  const float* hp = hr + ((size_t)bl*8 + h)*128 + c32*4;
  const float* gp = g + (size_t)bl*1024 + h*128 + c32*4;
  float4 v = *(const float4*)hp;
  float s = v.x + v.y + v.z + v.w;
  #pragma unroll
  for (int off = 16; off >= 1; off >>= 1) s += __shfl_xor(s, off);
  float mean = s * (1.f/128.f);
  float dx = v.x - mean, dy = v.y - mean, dz = v.z - mean, dw = v.w - mean;
  float ss = dx*dx + dy*dy + dz*dz + dw*dw;
  #pragma unroll
  for (int off = 16; off >= 1; off >>= 1) ss += __shfl_xor(ss, off);
  float inv = rsqrtf(ss * (1.f/128.f) + 1e-5f);
  float w = gn_w[h] * inv, bb = gn_b[h];
  float4 gv = *(const float4*)gp;
  float4 o;
  o.x = (dx*w + bb) * (gv.x / (1.f + expf(-gv.x)));
  o.y = (dy*w + bb) * (gv.y / (1.f + expf(-gv.y)));
  o.z = (dz*w + bb) * (gv.z / (1.f + expf(-gv.z)));
  o.w = (dw*w + bb) * (gv.w / (1.f + expf(-gv.w)));
  ushort4 oh, ol;
  split_bf16(o.x, oh.x, ol.x);
  split_bf16(o.y, oh.y, ol.y);
  split_bf16(o.z, oh.z, ol.z);
  split_bf16(o.w, oh.w, ol.w);
  size_t idx = (size_t)bl*1024 + h*128 + c32*4;
  *(ushort4*)(hnh + idx) = oh;
  *(ushort4*)(hnl + idx) = ol;
}

extern "C" void kernel_launch(void* const* d_in, const int* in_sizes, int n_in,
                              void* d_out, int out_size, void* d_ws, size_t ws_size,
                              hipStream_t stream) {
  const float* x        = (const float*)d_in[0];
  const float* hidden_r = (const float*)d_in[1];
  const float* hidden_i = (const float*)d_in[2];
  const float* W_qkv    = (const float*)d_in[3];
  const float* b_qkv    = (const float*)d_in[4];
  const float* W_g      = (const float*)d_in[5];
  const float* b_g      = (const float*)d_in[6];
  const float* W_aang   = (const float*)d_in[7];
  const float* b_aang   = (const float*)d_in[8];
  const float* W_lnabs  = (const float*)d_in[9];
  const float* b_lnabs  = (const float*)d_in[10];
  const float* W_pscale = (const float*)d_in[11];
  const float* b_pscale = (const float*)d_in[12];
  const float* W_y      = (const float*)d_in[13];
  const float* b_y      = (const float*)d_in[14];
  const float* gn_w     = (const float*)d_in[15];
  const float* gn_b     = (const float*)d_in[16];

  float* ws = (float*)d_ws;
  float* t_buf  = ws;
  float* hr_buf = t_buf;
  float* T_buf  = t_buf + 2097152;
  float* S_buf  = t_buf + 4194304;
  u16*   hnh    = (u16*)(t_buf + 2097152);
  u16*   hnl    = (u16*)(t_buf + 2097152) + 2097152;
  float* g_buf  = ws + 6291456;
  u16*   Wch    = (u16*)(ws + 8388608);
  u16*   Wcl    = Wch + 4194304;
  float* qp_buf = ws + 8388608;
  float* kp_buf = ws + 10485760;
  u16*   xh     = (u16*)(ws + 12582912);
  u16*   xl     = xh + 2097152;
  float* v_buf  = ws + 12582912;
  u16*   Wyh    = (u16*)(ws + 14680064);
  u16*   Wyl    = Wyh + 1048576;
  float* lnA    = ws + 15728640;
  float* scaleq = lnA + 32768;
  float* A_buf  = scaleq + 16384;

  float* y_out  = (float*)d_out;
  float* hid_re = (float*)d_out + 2097152;
  float* hid_im = (float*)d_out + 2097152 + 65536;
  int write_imag = (out_size >= 2097152 + 2*65536) ? 1 : 0;

  // 0) conversions
  k_convert<<<2048, 256, 0, stream>>>(x, xh, xl, 2097152);
  k_convert<<<3072, 256, 0, stream>>>(W_qkv, Wch, Wcl, 3145728);
  k_convert<<<1024, 256, 0, stream>>>(W_g, Wch + 3145728, Wcl + 3145728, 1048576);
  k_convert<<<1024, 256, 0, stream>>>(W_y, Wyh, Wyl, 1048576);

  // 1) fused [t|g] = x @ [W_qkv;W_g]^T + bias
  k_gemm_bs<128,128><<<dim3(4096/128, 2048/128), 256, 0, stream>>>(
      xh, xl, Wch, Wcl, b_qkv, b_g, 3072, t_buf, g_buf, 3072, 1024, 2048, 4096, 1024);
  // 2) small projections
  k_small_proj<<<2048, 256, 0, stream>>>(x, W_aang, b_aang, W_lnabs, b_lnabs, W_pscale, b_pscale, lnA, scaleq);
  // 3) cumsum
  k_cumsum<<<16, 1024, 0, stream>>>(lnA, A_buf);
  // 4) t -> qp, kp, v
  k_transform<<<2048, 256, 0, stream>>>(t_buf, scaleq, qp_buf, kp_buf, v_buf);
  // 5) per-chunk KV states
  k_chunkT<<<256, 256, 0, stream>>>(kp_buf, v_buf, A_buf, T_buf);
  // 6) element-parallel state reconstruction + hidden_next (256 blocks)
  k_states<<<256, 256, 0, stream>>>(hidden_r, hidden_i, A_buf, T_buf, S_buf, hid_re, hid_im, write_imag);
  // 7) per-chunk attention, 2 blocks per chunk
  k_attn<<<512, 256, 0, stream>>>(qp_buf, kp_buf, v_buf, A_buf, S_buf, hr_buf);
  // 8) GroupNorm * silu(g) -> bf16 hi/lo
  k_gn<<<2048, 256, 0, stream>>>(g_buf, hr_buf, gn_w, gn_b, hnh, hnl);
  // 9) y = hn @ W_y^T + b_y
  k_gemm_bs<64,64><<<dim3(1024/64, 2048/64), 256, 0, stream>>>(
      hnh, hnl, Wyh, Wyl, b_y, b_y, 1024, y_out, y_out, 1024, 1024, 2048, 1024, 1024);
}